// Round 1
// baseline (238.961 us; speedup 1.0000x reference)
//
#include <hip/hip_runtime.h>

// Fused UnifiedQCNNKernelClassifier:
//   h = tanh(W1 x+b1) -> tanh(W2 h+b2) -> tanh(W3 h+b3) -> tanh(W4 h+b4)
//     -> tanh(W5 h+b5) -> cls = Wh h + bh
//   k = exp(-gamma*|cls|^2); combined = [cls, 0,0,0,0, k]
//   out = log_softmax(Wf combined + bf)
//
// B = 2,097,152 samples, all dims tiny => fully-unrolled per-lane compute.
// Weights are wave-uniform loads (compiler scalarizes to s_load + SGPR-FMA).

constexpr int TPB = 256;
constexpr int S = 2;  // samples per thread

__device__ __forceinline__ float fexp(float x) {            // e^x
  return __builtin_amdgcn_exp2f(x * 1.4426950408889634f);
}
__device__ __forceinline__ float ftanh(float x) {
  // tanh(x) = 1 - 2/(e^{2x}+1); NaN-safe at +/-inf (rcp(inf)=0)
  float e = __builtin_amdgcn_exp2f(x * 2.8853900817779268f); // e^{2x}
  return 1.0f - 2.0f * __builtin_amdgcn_rcpf(e + 1.0f);
}

template <int F, int G, bool DOTANH>
__device__ __forceinline__ void dense(const float* __restrict__ W,
                                      const float* __restrict__ b,
                                      const float (&in)[S][16],
                                      float (&out)[S][16]) {
#pragma unroll
  for (int j = 0; j < G; ++j) {
    float wr[F];
#pragma unroll
    for (int i = 0; i < F; ++i) wr[i] = W[j * F + i];  // uniform -> SGPR
    const float bj = b[j];
#pragma unroll
    for (int s = 0; s < S; ++s) {
      float acc = bj;
#pragma unroll
      for (int i = 0; i < F; ++i) acc = fmaf(in[s][i], wr[i], acc);
      out[s][j] = DOTANH ? ftanh(acc) : acc;
    }
  }
}

__global__ __launch_bounds__(TPB) void qcnn_fused(
    const float* __restrict__ x,
    const float* __restrict__ W1, const float* __restrict__ b1,
    const float* __restrict__ W2, const float* __restrict__ b2,
    const float* __restrict__ W3, const float* __restrict__ b3,
    const float* __restrict__ W4, const float* __restrict__ b4,
    const float* __restrict__ W5, const float* __restrict__ b5,
    const float* __restrict__ Wh, const float* __restrict__ bh,
    const float* __restrict__ Wf, const float* __restrict__ bf,
    const float* __restrict__ gammap,
    float* __restrict__ out, int n) {
  const int base = blockIdx.x * (TPB * S) + threadIdx.x;
  const float g = gammap[0];

  float h0[S][16], hA[S][16], hB[S][16];

#pragma unroll
  for (int s = 0; s < S; ++s) {
    const int smp = base + s * TPB;
    if (smp < n) {
      const float4* xp = reinterpret_cast<const float4*>(x) + (size_t)smp * 2;
      float4 a = xp[0];
      float4 c = xp[1];
      h0[s][0] = a.x; h0[s][1] = a.y; h0[s][2] = a.z; h0[s][3] = a.w;
      h0[s][4] = c.x; h0[s][5] = c.y; h0[s][6] = c.z; h0[s][7] = c.w;
    } else {
#pragma unroll
      for (int i = 0; i < 8; ++i) h0[s][i] = 0.0f;
    }
  }

  dense<8, 16, true>(W1, b1, h0, hA);
  dense<16, 16, true>(W2, b2, hA, hB);
  dense<16, 12, true>(W3, b3, hB, hA);
  dense<12, 8, true>(W4, b4, hA, hB);
  dense<8, 4, true>(W5, b5, hB, hA);
  dense<4, 4, false>(Wh, bh, hA, hB);  // cls_out in hB[s][0..3]

#pragma unroll
  for (int s = 0; s < S; ++s) {
    const int smp = base + s * TPB;
    if (smp >= n) continue;
    const float c0 = hB[s][0], c1 = hB[s][1], c2 = hB[s][2], c3 = hB[s][3];
    // qnn_out == 0, so diff = cls_out; k = exp(-g * |cls|^2)
    const float ss = fmaf(c0, c0, fmaf(c1, c1, fmaf(c2, c2, c3 * c3)));
    const float k = fexp(-g * ss);
    // combined = [c0..c3, 0,0,0,0, k]; Wf is [2][9] row-major
    float o0 = bf[0];
    o0 = fmaf(Wf[0], c0, o0); o0 = fmaf(Wf[1], c1, o0);
    o0 = fmaf(Wf[2], c2, o0); o0 = fmaf(Wf[3], c3, o0);
    o0 = fmaf(Wf[8], k, o0);
    float o1 = bf[1];
    o1 = fmaf(Wf[9],  c0, o1); o1 = fmaf(Wf[10], c1, o1);
    o1 = fmaf(Wf[11], c2, o1); o1 = fmaf(Wf[12], c3, o1);
    o1 = fmaf(Wf[17], k, o1);
    // log_softmax over 2 classes
    const float m = fmaxf(o0, o1);
    const float sum = fexp(o0 - m) + fexp(o1 - m);
    const float lse = m + __builtin_amdgcn_logf(sum) * 0.6931471805599453f;
    float2 r;
    r.x = o0 - lse;
    r.y = o1 - lse;
    reinterpret_cast<float2*>(out)[smp] = r;
  }
}

extern "C" void kernel_launch(void* const* d_in, const int* in_sizes, int n_in,
                              void* d_out, int out_size, void* d_ws, size_t ws_size,
                              hipStream_t stream) {
  const float* x  = (const float*)d_in[0];
  const float* W1 = (const float*)d_in[1];
  const float* b1 = (const float*)d_in[2];
  const float* W2 = (const float*)d_in[3];
  const float* b2 = (const float*)d_in[4];
  const float* W3 = (const float*)d_in[5];
  const float* b3 = (const float*)d_in[6];
  const float* W4 = (const float*)d_in[7];
  const float* b4 = (const float*)d_in[8];
  const float* W5 = (const float*)d_in[9];
  const float* b5 = (const float*)d_in[10];
  const float* Wh = (const float*)d_in[11];
  const float* bh = (const float*)d_in[12];
  const float* Wf = (const float*)d_in[13];
  const float* bf = (const float*)d_in[14];
  const float* gm = (const float*)d_in[15];

  const int n = in_sizes[0] / 8;  // BATCH
  const int grid = (n + TPB * S - 1) / (TPB * S);
  qcnn_fused<<<grid, TPB, 0, stream>>>(x, W1, b1, W2, b2, W3, b3, W4, b4,
                                       W5, b5, Wh, bh, Wf, bf, gm,
                                       (float*)d_out, n);
}